// Round 9
// baseline (1126.119 us; speedup 1.0000x reference)
//
#include <hip/hip_runtime.h>
#include <math.h>

#define HH 768
#define WW 768
#define NPIX (HH*WW)            // 589824
#define NRR 24
#define NCC 24
#define NCELL (NRR*NCC)         // 576
#define CTOPC 36
#define NB 2

typedef _Float16 half2v __attribute__((ext_vector_type(2)));
__device__ __forceinline__ half2v h2(unsigned int u) { return __builtin_bit_cast(half2v, u); }

// ws layout (float offsets)
#define OFF_WPKP   0            // 28*480 = 13440 u32: [chpair][d][ky][kx*6+oc] packed f16x2
#define OFF_FSUM   13440        // 2*576*18 = 20736
#define OFF_BOTP   34176        // 1152
#define OFF_TMEAN  35328        // 2*36*576 = 41472
#define OFF_PVAL   76800        // 576
#define OFF_BOUNDS 77376        // 96 ints

// ---------------- Kernel 0: weight pack (f16x2 channel pairs) + bounds ----------------
__global__ void prep_kernel(const float* __restrict__ w1, const float* __restrict__ w2,
                            const float* __restrict__ w3,
                            const int* __restrict__ row_ids, const int* __restrict__ col_ids,
                            unsigned int* __restrict__ wpku, int* __restrict__ bounds) {
  int t = blockIdx.x * 256 + threadIdx.x;
  if (t < 28*480) {
    int cp = t / 480; int r = t % 480;
    int d = r / 160; int r2 = r % 160;
    int ky = r2 / 32; int slot = r2 % 32;
    unsigned int v = 0;
    if (slot < 30) {
      int kx = slot / 6, oc = slot % 6;
      int ch0 = 2*cp, ch1 = ch0 + 1;
      const float* wsrc = (d == 0) ? w1 : ((d == 1) ? w2 : w3);
      float f0 = wsrc[((oc * 55 + ch0) * 5 + ky) * 5 + kx];
      float f1 = (ch1 < 55) ? wsrc[((oc * 55 + ch1) * 5 + ky) * 5 + kx] : 0.f;
      _Float16 g0 = (_Float16)f0, g1 = (_Float16)f1;   // RTNE
      unsigned short s0 = __builtin_bit_cast(unsigned short, g0);
      unsigned short s1 = __builtin_bit_cast(unsigned short, g1);
      v = (unsigned int)s0 | ((unsigned int)s1 << 16);
    }
    wpku[t] = v;
  }
  if (blockIdx.x == 0 && threadIdx.x < 48) {
    int tt = threadIdx.x;
    const int* ids = (tt < 24) ? row_ids : col_ids;
    int r = tt % 24;
    int s = HH, e = HH;
    for (int h = 0; h < HH; ++h) {
      int v = ids[h];
      if (v >= r && h < s) s = h;
      if (v >= r + 1 && h < e) e = h;
    }
    int base = (tt < 24) ? 0 : 48;
    bounds[base + r] = s;
    bounds[base + 24 + r] = e;
  }
}

// ---------------- Kernel A: merged 3-dilation 5x5 conv via v_dot2_f32_f16 ----------------
// 256 threads; tile 16 rows x 64 cols; thread = (row 0..15, 4-px strip 0..15).
// Channel-PAIR phases (28 phases): LDS holds f16x2 (ch0,ch1) per pixel -> each
// dot2 = 2 MACs, halving VALU issue, LDS reads, and LDS footprint vs fp32.
// Staging is reg-staged (fp32 -> cvt_pkrtz -> ds_write), T14 split: global loads
// issue BEFORE the consume (latency hidden under 1800 dot2), cvt+write after.
// LDS: 2 x 28 rows x 80 u32 = 17.9 KB.
__global__ __attribute__((amdgpu_flat_work_group_size(256, 256)))
           __attribute__((amdgpu_waves_per_eu(2, 3)))
void conv_kernel(
    const float* __restrict__ x, const unsigned int* __restrict__ wpku,
    const float* __restrict__ b1, const float* __restrict__ b2, const float* __restrict__ b3,
    float* __restrict__ out) {
  __shared__ __align__(16) unsigned int tile[2][2240];   // 28*80 u32 per buffer
  const int tid = threadIdx.x;
  const int b  = blockIdx.z;
  const int h0 = blockIdx.y * 16;
  const int w0 = blockIdx.x * 64;
  const float* xb = x + (size_t)b * 55 * NPIX;

  // --- load both channels' chunks into registers (issue-early) ---
  auto LOADG = [&](int cp, float4* ra, float4* rb) {
    const int ch0 = 2*cp, ch1 = ch0 + 1;
    const float* x0 = xb + (size_t)ch0 * NPIX;
    const float* x1 = xb + (size_t)ch1 * NPIX;
    #pragma unroll
    for (int k = 0; k < 3; ++k) {
      int idx = k*256 + tid;                 // u32x4-chunk index, 560 valid
      ra[k] = make_float4(0.f,0.f,0.f,0.f);
      rb[k] = make_float4(0.f,0.f,0.f,0.f);
      if (idx < 560) {
        int row = idx / 20, cc = (idx % 20) * 4;
        int gh = h0 - 6 + row, gw = w0 - 8 + cc;
        bool ok = (gh >= 0) & (gh < 768) & (gw >= 0) & (gw + 3 < 768);
        if (ok) {
          ra[k] = *(const float4*)(x0 + gh*768 + gw);
          if (ch1 < 55) rb[k] = *(const float4*)(x1 + gh*768 + gw);
        }
      }
    }
  };
  // --- convert + write to LDS (consume-late; vmcnt waits land here) ---
  auto WRITE = [&](int bufi, const float4* ra, const float4* rb) {
    #pragma unroll
    for (int k = 0; k < 3; ++k) {
      int idx = k*256 + tid;
      if (idx < 560) {
        uint4 w;
        w.x = __builtin_bit_cast(unsigned int, __builtin_amdgcn_cvt_pkrtz(ra[k].x, rb[k].x));
        w.y = __builtin_bit_cast(unsigned int, __builtin_amdgcn_cvt_pkrtz(ra[k].y, rb[k].y));
        w.z = __builtin_bit_cast(unsigned int, __builtin_amdgcn_cvt_pkrtz(ra[k].z, rb[k].z));
        w.w = __builtin_bit_cast(unsigned int, __builtin_amdgcn_cvt_pkrtz(ra[k].w, rb[k].w));
        *(uint4*)&tile[bufi][idx*4] = w;
      }
    }
  };

  float acc[18][4];
  #pragma unroll
  for (int i = 0; i < 18; ++i)
    #pragma unroll
    for (int p = 0; p < 4; ++p) acc[i][p] = 0.f;

  const int r6 = (tid >> 4) + 6;   // tap-row base
  const int c  = tid & 15;         // 4-px strip (quarter-wave = one LDS row)

#define TAPS(D, KY, BASE) \
  { const unsigned int* wr = wchp + ((D-1)*5 + (KY))*32; \
    _Pragma("unroll") for (int kx = 0; kx < 5; ++kx) { \
      _Pragma("unroll") for (int oc = 0; oc < 6; ++oc) { \
        const half2v wv = h2(wr[kx*6+oc]); \
        _Pragma("unroll") for (int p = 0; p < 4; ++p) \
          acc[(D-1)*6+oc][p] = __builtin_amdgcn_fdot2( \
              h2(sp2[(BASE) + p + (kx-2)*(D)]), wv, acc[(D-1)*6+oc][p], false); } } }

  // wide: 5 chunks from chunk (c+0) -> u32 [4c, 4c+20)   : tap base 8
  // med : 3 chunks from chunk (c+1) -> u32 [4c+4, 4c+16) : tap base 4
#define LOADW(O) { const uint4* rp = (const uint4*)&tb[(r6 + (O))*80] + c; \
    *(uint4*)&sp2[0]  = rp[0]; *(uint4*)&sp2[4]  = rp[1]; *(uint4*)&sp2[8] = rp[2]; \
    *(uint4*)&sp2[12] = rp[3]; *(uint4*)&sp2[16] = rp[4]; }
#define LOADM(O) { const uint4* rp = (const uint4*)&tb[(r6 + (O))*80] + c + 1; \
    *(uint4*)&sp2[0] = rp[0]; *(uint4*)&sp2[4] = rp[1]; *(uint4*)&sp2[8] = rp[2]; }

  {
    float4 ra[3], rb[3];
    LOADG(0, ra, rb);
    WRITE(0, ra, rb);
  }
  __syncthreads();
  int cur = 0;
  for (int cp = 0; cp < 28; ++cp) {
    float4 na[3], nb[3];
    if (cp < 27) LOADG(cp + 1, na, nb);     // loads in flight across the consume
    const unsigned int* tb = &tile[cur][0];
    const unsigned int* wchp = wpku + cp * 480;
    unsigned int sp2[20];
    LOADW(-6); TAPS(3,0,8)
    LOADM(-4); TAPS(2,0,4)
    LOADW(-3); TAPS(3,1,8)
    LOADM(-2); TAPS(1,0,4) TAPS(2,1,4)
    LOADM(-1); TAPS(1,1,4)
    LOADW( 0); TAPS(1,2,8) TAPS(2,2,8) TAPS(3,2,8)
    LOADM( 1); TAPS(1,3,4)
    LOADM( 2); TAPS(1,4,4) TAPS(2,3,4)
    LOADW( 3); TAPS(3,3,8)
    LOADM( 4); TAPS(2,4,4)
    LOADW( 6); TAPS(3,4,8)
    if (cp < 27) WRITE(cur ^ 1, na, nb);    // cvt+ds_write to the other buffer
    __syncthreads();
    cur ^= 1;
  }
#undef TAPS
#undef LOADW
#undef LOADM

  const int gr = h0 + (r6 - 6), gcol = w0 + c*4;
  #pragma unroll
  for (int d = 0; d < 3; ++d) {
    const float* bp = (d == 0) ? b1 : ((d == 1) ? b2 : b3);
    #pragma unroll
    for (int oc = 0; oc < 6; ++oc) {
      const float bias = bp[oc];
      float4 v;
      v.x = fmaxf(acc[d*6+oc][0] + bias, 0.f);
      v.y = fmaxf(acc[d*6+oc][1] + bias, 0.f);
      v.z = fmaxf(acc[d*6+oc][2] + bias, 0.f);
      v.w = fmaxf(acc[d*6+oc][3] + bias, 0.f);
      *(float4*)(out + ((size_t)(b*55 + 36 + d*6 + oc))*NPIX + gr*768 + gcol) = v;
    }
  }
}

// ---------------- Kernel B: per-cell sums of features + sigmoid(bot) ----------------
__global__ __launch_bounds__(256) void cellsum_kernel(const float* __restrict__ dout,
    const int* __restrict__ bounds,
    const float* __restrict__ w_bot, const float* __restrict__ b_bot,
    float* __restrict__ feat_sums, float* __restrict__ bot_partial) {
  int blk = blockIdx.x;                       // b*576 + r*24 + c
  int b = blk / NCELL; int rc = blk % NCELL; int r = rc / NCC, c = rc % NCC;
  int rs = bounds[r], re = bounds[24 + r], cs = bounds[48 + c], ce = bounds[72 + c];
  int cw = ce - cs;
  int npix = (re - rs) * cw;
  float facc[18];
  #pragma unroll
  for (int k = 0; k < 18; ++k) facc[k] = 0.f;
  float sacc = 0.f;
  float wb[18];
  #pragma unroll
  for (int k = 0; k < 18; ++k) wb[k] = w_bot[k];
  float bb = b_bot[0];
  const float* fb = dout + ((size_t)b * 55 + 36) * NPIX;
  for (int i = threadIdx.x; i < npix; i += 256) {
    int hh = rs + i / cw, ww = cs + i % cw;
    int pix = hh * WW + ww;
    float dot = bb;
    #pragma unroll
    for (int k = 0; k < 18; ++k) {
      float v = fb[(size_t)k * NPIX + pix];
      facc[k] += v;
      dot += wb[k] * v;
    }
    sacc += 1.f / (1.f + expf(-dot));
  }
  #pragma unroll
  for (int k = 0; k < 18; ++k) {
    #pragma unroll
    for (int off = 32; off; off >>= 1) facc[k] += __shfl_xor(facc[k], off);
  }
  #pragma unroll
  for (int off = 32; off; off >>= 1) sacc += __shfl_xor(sacc, off);
  __shared__ float red[4][19];
  int wv = threadIdx.x >> 6, ln = threadIdx.x & 63;
  if (ln == 0) {
    #pragma unroll
    for (int k = 0; k < 18; ++k) red[wv][k] = facc[k];
    red[wv][18] = sacc;
  }
  __syncthreads();
  if (threadIdx.x < 19) {
    float s = red[0][threadIdx.x] + red[1][threadIdx.x] + red[2][threadIdx.x] + red[3][threadIdx.x];
    if (threadIdx.x < 18) feat_sums[(size_t)blk * 18 + threadIdx.x] = s;
    else bot_partial[blk] = s;
  }
}

// ---------------- Kernel C: cell means (top) + pools ----------------
__global__ void cellmean_kernel(const float* __restrict__ feat_sums,
    const float* __restrict__ bot_partial, const int* __restrict__ bounds,
    const float* __restrict__ w_top, const float* __restrict__ b_top,
    float* __restrict__ top_means, float* __restrict__ pools_val, float* __restrict__ dout) {
  int t = blockIdx.x * 256 + threadIdx.x;
  if (t < NB * CTOPC * NCELL) {
    int c = t % NCC, r = (t / NCC) % NRR, k = (t / NCELL) % CTOPC, b = t / (NCELL * CTOPC);
    int cnt = (bounds[24 + r] - bounds[r]) * (bounds[72 + c] - bounds[48 + c]);
    float v = 0.f;
    if (cnt > 0) {
      const float* fs = feat_sums + ((size_t)(b * NCELL + r * NCC + c)) * 18;
      float dot = 0.f;
      #pragma unroll
      for (int i = 0; i < 18; ++i) dot += w_top[k * 18 + i] * fs[i];
      v = dot / (float)cnt + b_top[k];
    }
    top_means[t] = v;   // [b][k][r][c]
  }
  int t2 = t - NB * CTOPC * NCELL;
  if (t2 >= 0 && t2 < NCELL) {
    int r = t2 / NCC, c = t2 % NCC;
    int cnt = (bounds[24 + r] - bounds[r]) * (bounds[72 + c] - bounds[48 + c]);
    if (cnt < 1) cnt = 1;
    float v = (bot_partial[t2] + bot_partial[NCELL + t2]) / (2.f * (float)cnt);
    pools_val[t2] = v;
    dout[(size_t)NB * 55 * NPIX + t2] = v;           // pools b=0
    dout[(size_t)NB * 55 * NPIX + NCELL + t2] = v;   // pools b=1
  }
}

// ---------------- Kernel D: broadcast top means + bottom value ----------------
__global__ __launch_bounds__(256) void bcast_kernel(const float* __restrict__ top_means,
    const float* __restrict__ pools_val, const int* __restrict__ row_ids,
    const int* __restrict__ col_ids, float* __restrict__ out) {
  int w = blockIdx.x * 256 + threadIdx.x;
  int h = blockIdx.y;
  int b = blockIdx.z;
  int r = row_ids[h], c = col_ids[w];
  int pix = h * 768 + w;
  float* ob = out + (size_t)b * 55 * NPIX + pix;
  const float* tm = top_means + (size_t)b * CTOPC * NCELL + r * NCC + c;
  #pragma unroll
  for (int k = 0; k < 36; ++k) ob[(size_t)k * NPIX] = tm[(size_t)k * NCELL];
  ob[(size_t)54 * NPIX] = pools_val[r * NCC + c];
}

extern "C" void kernel_launch(void* const* d_in, const int* in_sizes, int n_in,
                              void* d_out, int out_size, void* d_ws, size_t ws_size,
                              hipStream_t stream) {
  const float* x      = (const float*)d_in[0];
  const int* row_ids  = (const int*)d_in[1];
  const int* col_ids  = (const int*)d_in[2];
  const float* w1     = (const float*)d_in[5];
  const float* b1     = (const float*)d_in[6];
  const float* w2     = (const float*)d_in[7];
  const float* b2     = (const float*)d_in[8];
  const float* w3     = (const float*)d_in[9];
  const float* b3     = (const float*)d_in[10];
  const float* w_top  = (const float*)d_in[11];
  const float* b_top  = (const float*)d_in[12];
  const float* w_bot  = (const float*)d_in[13];
  const float* b_bot  = (const float*)d_in[14];
  float* out = (float*)d_out;
  float* ws  = (float*)d_ws;

  unsigned int* wpku = (unsigned int*)(ws + OFF_WPKP);
  float* feat_sums   = ws + OFF_FSUM;
  float* bot_partial = ws + OFF_BOTP;
  float* top_means   = ws + OFF_TMEAN;
  float* pools_val   = ws + OFF_PVAL;
  int*   bounds      = (int*)(ws + OFF_BOUNDS);

  hipLaunchKernelGGL(prep_kernel, dim3(53), dim3(256), 0, stream,
                     w1, w2, w3, row_ids, col_ids, wpku, bounds);
  hipLaunchKernelGGL(conv_kernel, dim3(12, 48, 2), dim3(256), 0, stream,
                     x, wpku, b1, b2, b3, out);
  hipLaunchKernelGGL(cellsum_kernel, dim3(NB * NCELL), dim3(256), 0, stream,
                     out, bounds, w_bot, b_bot, feat_sums, bot_partial);
  hipLaunchKernelGGL(cellmean_kernel, dim3(165), dim3(256), 0, stream,
                     feat_sums, bot_partial, bounds, w_top, b_top, top_means, pools_val, out);
  hipLaunchKernelGGL(bcast_kernel, dim3(3, 768, 2), dim3(256), 0, stream,
                     top_means, pools_val, row_ids, col_ids, out);
}

// Round 10
// 789.922 us; speedup vs baseline: 1.4256x; 1.4256x over previous
//
#include <hip/hip_runtime.h>
#include <math.h>

#define HH 768
#define WW 768
#define NPIX (HH*WW)            // 589824
#define NRR 24
#define NCC 24
#define NCELL (NRR*NCC)         // 576
#define CTOPC 36
#define NB 2

typedef _Float16 half2v __attribute__((ext_vector_type(2)));
__device__ __forceinline__ half2v h2(unsigned int u) { return __builtin_bit_cast(half2v, u); }

// f16x2 temp images live in spare d_out regions: img i (=b*28+cp, NPIX u32 each):
// i<36 -> out image i (b0 ch0-35); i>=36 -> out image i+19 (b1 ch0-19).
// Disjoint from conv outputs (imgs 36-53, 91-108); fully overwritten by bcast later.
__device__ __host__ __forceinline__ size_t img_off(int i) {
  return (size_t)(i < 36 ? i : i + 19) * NPIX;
}

// ws layout (float offsets)
#define OFF_WPKP   0            // 28*480 = 13440 u32: [chpair][d][ky][kx*6+oc] packed f16x2
#define OFF_ZP     13440        // 256 u32 zeros (OOB staging target)
#define OFF_FSUM   13696        // 2*576*18 = 20736
#define OFF_BOTP   34432        // 1152
#define OFF_TMEAN  35584        // 2*36*576 = 41472
#define OFF_PVAL   77056        // 576
#define OFF_BOUNDS 77632        // 96 ints

// ---------------- Kernel 0: weight pack (f16x2 channel pairs) + bounds + zp ----------------
__global__ void prep_kernel(const float* __restrict__ w1, const float* __restrict__ w2,
                            const float* __restrict__ w3,
                            const int* __restrict__ row_ids, const int* __restrict__ col_ids,
                            unsigned int* __restrict__ wpku, unsigned int* __restrict__ zp,
                            int* __restrict__ bounds) {
  int t = blockIdx.x * 256 + threadIdx.x;
  if (t < 28*480) {
    int cp = t / 480; int r = t % 480;
    int d = r / 160; int r2 = r % 160;
    int ky = r2 / 32; int slot = r2 % 32;
    unsigned int v = 0;
    if (slot < 30) {
      int kx = slot / 6, oc = slot % 6;
      int ch0 = 2*cp, ch1 = ch0 + 1;
      const float* wsrc = (d == 0) ? w1 : ((d == 1) ? w2 : w3);
      float f0 = wsrc[((oc * 55 + ch0) * 5 + ky) * 5 + kx];
      float f1 = (ch1 < 55) ? wsrc[((oc * 55 + ch1) * 5 + ky) * 5 + kx] : 0.f;
      _Float16 g0 = (_Float16)f0, g1 = (_Float16)f1;   // RTNE
      unsigned short s0 = __builtin_bit_cast(unsigned short, g0);
      unsigned short s1 = __builtin_bit_cast(unsigned short, g1);
      v = (unsigned int)s0 | ((unsigned int)s1 << 16);
    }
    wpku[t] = v;
  }
  if (blockIdx.x == 1 && threadIdx.x < 256) zp[threadIdx.x] = 0u;
  if (blockIdx.x == 0 && threadIdx.x < 48) {
    int tt = threadIdx.x;
    const int* ids = (tt < 24) ? row_ids : col_ids;
    int r = tt % 24;
    int s = HH, e = HH;
    for (int h = 0; h < HH; ++h) {
      int v = ids[h];
      if (v >= r && h < s) s = h;
      if (v >= r + 1 && h < e) e = h;
    }
    int base = (tt < 24) ? 0 : 48;
    bounds[base + r] = s;
    bounds[base + 24 + r] = e;
  }
}

// ---------------- Kernel P: fp32 x -> channel-paired f16x2 temp images ----------------
__global__ __launch_bounds__(256) void cvt_kernel(const float* __restrict__ x,
                                                  unsigned int* __restrict__ outU) {
  const int img = blockIdx.y;
  const int b = img / 28, cp = img % 28;
  const int p4 = (blockIdx.x * 256 + threadIdx.x) * 4;
  const float* x0 = x + ((size_t)b * 55 + 2*cp) * NPIX + p4;
  float4 a = *(const float4*)x0;
  float4 c = make_float4(0.f, 0.f, 0.f, 0.f);
  if (2*cp + 1 < 55) c = *(const float4*)(x0 + NPIX);
  uint4 w;
  w.x = __builtin_bit_cast(unsigned int, __builtin_amdgcn_cvt_pkrtz(a.x, c.x));
  w.y = __builtin_bit_cast(unsigned int, __builtin_amdgcn_cvt_pkrtz(a.y, c.y));
  w.z = __builtin_bit_cast(unsigned int, __builtin_amdgcn_cvt_pkrtz(a.z, c.z));
  w.w = __builtin_bit_cast(unsigned int, __builtin_amdgcn_cvt_pkrtz(a.w, c.w));
  *(uint4*)(outU + img_off(img) + p4) = w;
}

// ---------------- Kernel A: merged 3-dilation 5x5 conv via v_dot2_f32_f16 ----------------
// Round-6 schedule (global_load_lds staging, 28 phases, double buffer) on f16x2 data:
// half the staging bytes, half the LDS reads, half the VALU issue of the fp32 version.
// LDS: 2 x 768 chunks x 16B = 24.6 KB. Tile 16x64, thread = (row, 4-px strip).
__global__ __attribute__((amdgpu_flat_work_group_size(256, 256)))
           __attribute__((amdgpu_waves_per_eu(2, 4)))
void conv_kernel(
    const unsigned int* __restrict__ xu, const unsigned int* __restrict__ wpku,
    const unsigned int* __restrict__ zp,
    const float* __restrict__ b1, const float* __restrict__ b2, const float* __restrict__ b3,
    float* __restrict__ out) {
  __shared__ __align__(16) unsigned int tile[2][3072];   // 768 chunks x 4 u32 per buffer
  const int tid = threadIdx.x;
  const int b  = blockIdx.z;
  const int h0 = blockIdx.y * 16;
  const int w0 = blockIdx.x * 64;

  auto STAGE = [&](int bufi, int cp) {
    const unsigned int* xc = xu + img_off(b*28 + cp);
    #pragma unroll
    for (int k = 0; k < 3; ++k) {
      int idx = k*256 + tid;                 // chunk 0..767; rows>=28 land in LDS pad
      int row = idx / 20, cc = (idx % 20) * 4;
      int gh = h0 - 6 + row, gw = w0 - 8 + cc;
      bool ok = (gh >= 0) & (gh < 768) & (gw >= 0) & (gw + 3 < 768) & (row < 28);
      const unsigned int* src = ok ? (xc + gh*768 + gw) : (zp + (tid & 63)*4);
      unsigned int* dst = &tile[bufi][(k*256 + (tid & ~63))*4];  // wave-uniform base
      __builtin_amdgcn_global_load_lds(
          (const __attribute__((address_space(1))) void*)src,
          (__attribute__((address_space(3))) void*)dst, 16, 0, 0);
    }
  };

  float acc[18][4];
  #pragma unroll
  for (int i = 0; i < 18; ++i)
    #pragma unroll
    for (int p = 0; p < 4; ++p) acc[i][p] = 0.f;

  const int r6 = (tid >> 4) + 6;   // tap-row base
  const int c  = tid & 15;         // 4-px strip (quarter-wave = one LDS row)

#define TAPS(D, KY, BASE) \
  { const unsigned int* wr = wchp + ((D-1)*5 + (KY))*32; \
    _Pragma("unroll") for (int kx = 0; kx < 5; ++kx) { \
      _Pragma("unroll") for (int oc = 0; oc < 6; ++oc) { \
        const half2v wv = h2(wr[kx*6+oc]); \
        _Pragma("unroll") for (int p = 0; p < 4; ++p) \
          acc[(D-1)*6+oc][p] = __builtin_amdgcn_fdot2( \
              h2(sp2[(BASE) + p + (kx-2)*(D)]), wv, acc[(D-1)*6+oc][p], false); } } }

  // wide: 5 chunks from chunk (c+0) -> u32 [4c, 4c+20)   : tap base 8
  // med : 3 chunks from chunk (c+1) -> u32 [4c+4, 4c+16) : tap base 4
#define LOADW(O) { const uint4* rp = (const uint4*)&tb[(r6 + (O))*80] + c; \
    *(uint4*)&sp2[0]  = rp[0]; *(uint4*)&sp2[4]  = rp[1]; *(uint4*)&sp2[8] = rp[2]; \
    *(uint4*)&sp2[12] = rp[3]; *(uint4*)&sp2[16] = rp[4]; }
#define LOADM(O) { const uint4* rp = (const uint4*)&tb[(r6 + (O))*80] + c + 1; \
    *(uint4*)&sp2[0] = rp[0]; *(uint4*)&sp2[4] = rp[1]; *(uint4*)&sp2[8] = rp[2]; }

  STAGE(0, 0);
  __syncthreads();
  int cur = 0;
  for (int cp = 0; cp < 28; ++cp) {
    if (cp < 27) STAGE(cur ^ 1, cp + 1);    // loads in flight across the consume
    const unsigned int* tb = &tile[cur][0];
    const unsigned int* wchp = wpku + cp * 480;
    unsigned int sp2[20];
    LOADW(-6); TAPS(3,0,8)
    LOADM(-4); TAPS(2,0,4)
    LOADW(-3); TAPS(3,1,8)
    LOADM(-2); TAPS(1,0,4) TAPS(2,1,4)
    LOADM(-1); TAPS(1,1,4)
    LOADW( 0); TAPS(1,2,8) TAPS(2,2,8) TAPS(3,2,8)
    LOADM( 1); TAPS(1,3,4)
    LOADM( 2); TAPS(1,4,4) TAPS(2,3,4)
    LOADW( 3); TAPS(3,3,8)
    LOADM( 4); TAPS(2,4,4)
    LOADW( 6); TAPS(3,4,8)
    __syncthreads();
    cur ^= 1;
  }
#undef TAPS
#undef LOADW
#undef LOADM

  const int gr = h0 + (r6 - 6), gcol = w0 + c*4;
  #pragma unroll
  for (int d = 0; d < 3; ++d) {
    const float* bp = (d == 0) ? b1 : ((d == 1) ? b2 : b3);
    #pragma unroll
    for (int oc = 0; oc < 6; ++oc) {
      const float bias = bp[oc];
      float4 v;
      v.x = fmaxf(acc[d*6+oc][0] + bias, 0.f);
      v.y = fmaxf(acc[d*6+oc][1] + bias, 0.f);
      v.z = fmaxf(acc[d*6+oc][2] + bias, 0.f);
      v.w = fmaxf(acc[d*6+oc][3] + bias, 0.f);
      *(float4*)(out + ((size_t)(b*55 + 36 + d*6 + oc))*NPIX + gr*768 + gcol) = v;
    }
  }
}

// ---------------- Kernel B: per-cell sums of features + sigmoid(bot) ----------------
__global__ __launch_bounds__(256) void cellsum_kernel(const float* __restrict__ dout,
    const int* __restrict__ bounds,
    const float* __restrict__ w_bot, const float* __restrict__ b_bot,
    float* __restrict__ feat_sums, float* __restrict__ bot_partial) {
  int blk = blockIdx.x;                       // b*576 + r*24 + c
  int b = blk / NCELL; int rc = blk % NCELL; int r = rc / NCC, c = rc % NCC;
  int rs = bounds[r], re = bounds[24 + r], cs = bounds[48 + c], ce = bounds[72 + c];
  int cw = ce - cs;
  int npix = (re - rs) * cw;
  float facc[18];
  #pragma unroll
  for (int k = 0; k < 18; ++k) facc[k] = 0.f;
  float sacc = 0.f;
  float wb[18];
  #pragma unroll
  for (int k = 0; k < 18; ++k) wb[k] = w_bot[k];
  float bb = b_bot[0];
  const float* fb = dout + ((size_t)b * 55 + 36) * NPIX;
  for (int i = threadIdx.x; i < npix; i += 256) {
    int hh = rs + i / cw, ww = cs + i % cw;
    int pix = hh * WW + ww;
    float dot = bb;
    #pragma unroll
    for (int k = 0; k < 18; ++k) {
      float v = fb[(size_t)k * NPIX + pix];
      facc[k] += v;
      dot += wb[k] * v;
    }
    sacc += 1.f / (1.f + expf(-dot));
  }
  #pragma unroll
  for (int k = 0; k < 18; ++k) {
    #pragma unroll
    for (int off = 32; off; off >>= 1) facc[k] += __shfl_xor(facc[k], off);
  }
  #pragma unroll
  for (int off = 32; off; off >>= 1) sacc += __shfl_xor(sacc, off);
  __shared__ float red[4][19];
  int wv = threadIdx.x >> 6, ln = threadIdx.x & 63;
  if (ln == 0) {
    #pragma unroll
    for (int k = 0; k < 18; ++k) red[wv][k] = facc[k];
    red[wv][18] = sacc;
  }
  __syncthreads();
  if (threadIdx.x < 19) {
    float s = red[0][threadIdx.x] + red[1][threadIdx.x] + red[2][threadIdx.x] + red[3][threadIdx.x];
    if (threadIdx.x < 18) feat_sums[(size_t)blk * 18 + threadIdx.x] = s;
    else bot_partial[blk] = s;
  }
}

// ---------------- Kernel C: cell means (top) + pools ----------------
__global__ void cellmean_kernel(const float* __restrict__ feat_sums,
    const float* __restrict__ bot_partial, const int* __restrict__ bounds,
    const float* __restrict__ w_top, const float* __restrict__ b_top,
    float* __restrict__ top_means, float* __restrict__ pools_val, float* __restrict__ dout) {
  int t = blockIdx.x * 256 + threadIdx.x;
  if (t < NB * CTOPC * NCELL) {
    int c = t % NCC, r = (t / NCC) % NRR, k = (t / NCELL) % CTOPC, b = t / (NCELL * CTOPC);
    int cnt = (bounds[24 + r] - bounds[r]) * (bounds[72 + c] - bounds[48 + c]);
    float v = 0.f;
    if (cnt > 0) {
      const float* fs = feat_sums + ((size_t)(b * NCELL + r * NCC + c)) * 18;
      float dot = 0.f;
      #pragma unroll
      for (int i = 0; i < 18; ++i) dot += w_top[k * 18 + i] * fs[i];
      v = dot / (float)cnt + b_top[k];
    }
    top_means[t] = v;   // [b][k][r][c]
  }
  int t2 = t - NB * CTOPC * NCELL;
  if (t2 >= 0 && t2 < NCELL) {
    int r = t2 / NCC, c = t2 % NCC;
    int cnt = (bounds[24 + r] - bounds[r]) * (bounds[72 + c] - bounds[48 + c]);
    if (cnt < 1) cnt = 1;
    float v = (bot_partial[t2] + bot_partial[NCELL + t2]) / (2.f * (float)cnt);
    pools_val[t2] = v;
    dout[(size_t)NB * 55 * NPIX + t2] = v;           // pools b=0
    dout[(size_t)NB * 55 * NPIX + NCELL + t2] = v;   // pools b=1
  }
}

// ---------------- Kernel D: broadcast top means + bottom value ----------------
__global__ __launch_bounds__(256) void bcast_kernel(const float* __restrict__ top_means,
    const float* __restrict__ pools_val, const int* __restrict__ row_ids,
    const int* __restrict__ col_ids, float* __restrict__ out) {
  int w = blockIdx.x * 256 + threadIdx.x;
  int h = blockIdx.y;
  int b = blockIdx.z;
  int r = row_ids[h], c = col_ids[w];
  int pix = h * 768 + w;
  float* ob = out + (size_t)b * 55 * NPIX + pix;
  const float* tm = top_means + (size_t)b * CTOPC * NCELL + r * NCC + c;
  #pragma unroll
  for (int k = 0; k < 36; ++k) ob[(size_t)k * NPIX] = tm[(size_t)k * NCELL];
  ob[(size_t)54 * NPIX] = pools_val[r * NCC + c];
}

extern "C" void kernel_launch(void* const* d_in, const int* in_sizes, int n_in,
                              void* d_out, int out_size, void* d_ws, size_t ws_size,
                              hipStream_t stream) {
  const float* x      = (const float*)d_in[0];
  const int* row_ids  = (const int*)d_in[1];
  const int* col_ids  = (const int*)d_in[2];
  const float* w1     = (const float*)d_in[5];
  const float* b1     = (const float*)d_in[6];
  const float* w2     = (const float*)d_in[7];
  const float* b2     = (const float*)d_in[8];
  const float* w3     = (const float*)d_in[9];
  const float* b3     = (const float*)d_in[10];
  const float* w_top  = (const float*)d_in[11];
  const float* b_top  = (const float*)d_in[12];
  const float* w_bot  = (const float*)d_in[13];
  const float* b_bot  = (const float*)d_in[14];
  float* out = (float*)d_out;
  float* ws  = (float*)d_ws;

  unsigned int* wpku = (unsigned int*)(ws + OFF_WPKP);
  unsigned int* zp   = (unsigned int*)(ws + OFF_ZP);
  float* feat_sums   = ws + OFF_FSUM;
  float* bot_partial = ws + OFF_BOTP;
  float* top_means   = ws + OFF_TMEAN;
  float* pools_val   = ws + OFF_PVAL;
  int*   bounds      = (int*)(ws + OFF_BOUNDS);
  unsigned int* outU = (unsigned int*)d_out;

  hipLaunchKernelGGL(prep_kernel, dim3(53), dim3(256), 0, stream,
                     w1, w2, w3, row_ids, col_ids, wpku, zp, bounds);
  hipLaunchKernelGGL(cvt_kernel, dim3(576, 56), dim3(256), 0, stream,
                     x, outU);
  hipLaunchKernelGGL(conv_kernel, dim3(12, 48, 2), dim3(256), 0, stream,
                     outU, wpku, zp, b1, b2, b3, out);
  hipLaunchKernelGGL(cellsum_kernel, dim3(NB * NCELL), dim3(256), 0, stream,
                     out, bounds, w_bot, b_bot, feat_sums, bot_partial);
  hipLaunchKernelGGL(cellmean_kernel, dim3(165), dim3(256), 0, stream,
                     feat_sums, bot_partial, bounds, w_top, b_top, top_means, pools_val, out);
  hipLaunchKernelGGL(bcast_kernel, dim3(3, 768, 2), dim3(256), 0, stream,
                     top_means, pools_val, row_ids, col_ids, out);
}

// Round 11
// 771.463 us; speedup vs baseline: 1.4597x; 1.0239x over previous
//
#include <hip/hip_runtime.h>
#include <math.h>

#define HH 768
#define WW 768
#define NPIX (HH*WW)            // 589824
#define NRR 24
#define NCC 24
#define NCELL (NRR*NCC)         // 576
#define CTOPC 36
#define NB 2

typedef _Float16 half2v __attribute__((ext_vector_type(2)));
__device__ __forceinline__ half2v h2(unsigned int u) { return __builtin_bit_cast(half2v, u); }

// f16x2 temp images live in spare d_out regions: img i (=b*28+cp, NPIX u32 each):
// i<36 -> out image i (b0 ch0-35); i>=36 -> out image i+19 (b1 ch0-19).
// Disjoint from conv outputs (imgs 36-53, 91-108); fully overwritten by bcast later.
__device__ __host__ __forceinline__ size_t img_off(int i) {
  return (size_t)(i < 36 ? i : i + 19) * NPIX;
}

// ws layout (float offsets)
#define OFF_WPKP   0            // 28*480 = 13440 u32: [chpair][d][ky][kx*6+oc] packed f16x2
#define OFF_ZP     13440        // 256 u32 zeros (OOB staging target)
#define OFF_FSUM   13696        // 2*576*18 = 20736
#define OFF_BOTP   34432        // 1152
#define OFF_TMEAN  35584        // 2*36*576 = 41472
#define OFF_PVAL   77056        // 576
#define OFF_BOUNDS 77632        // 96 ints

// ---------------- Kernel 0: weight pack (f16x2 channel pairs) + bounds + zp ----------------
__global__ void prep_kernel(const float* __restrict__ w1, const float* __restrict__ w2,
                            const float* __restrict__ w3,
                            const int* __restrict__ row_ids, const int* __restrict__ col_ids,
                            unsigned int* __restrict__ wpku, unsigned int* __restrict__ zp,
                            int* __restrict__ bounds) {
  int t = blockIdx.x * 256 + threadIdx.x;
  if (t < 28*480) {
    int cp = t / 480; int r = t % 480;
    int d = r / 160; int r2 = r % 160;
    int ky = r2 / 32; int slot = r2 % 32;
    unsigned int v = 0;
    if (slot < 30) {
      int kx = slot / 6, oc = slot % 6;
      int ch0 = 2*cp, ch1 = ch0 + 1;
      const float* wsrc = (d == 0) ? w1 : ((d == 1) ? w2 : w3);
      float f0 = wsrc[((oc * 55 + ch0) * 5 + ky) * 5 + kx];
      float f1 = (ch1 < 55) ? wsrc[((oc * 55 + ch1) * 5 + ky) * 5 + kx] : 0.f;
      _Float16 g0 = (_Float16)f0, g1 = (_Float16)f1;   // RTNE
      unsigned short s0 = __builtin_bit_cast(unsigned short, g0);
      unsigned short s1 = __builtin_bit_cast(unsigned short, g1);
      v = (unsigned int)s0 | ((unsigned int)s1 << 16);
    }
    wpku[t] = v;
  }
  if (blockIdx.x == 1 && threadIdx.x < 256) zp[threadIdx.x] = 0u;
  if (blockIdx.x == 0 && threadIdx.x < 48) {
    int tt = threadIdx.x;
    const int* ids = (tt < 24) ? row_ids : col_ids;
    int r = tt % 24;
    int s = HH, e = HH;
    for (int h = 0; h < HH; ++h) {
      int v = ids[h];
      if (v >= r && h < s) s = h;
      if (v >= r + 1 && h < e) e = h;
    }
    int base = (tt < 24) ? 0 : 48;
    bounds[base + r] = s;
    bounds[base + 24 + r] = e;
  }
}

// ---------------- Kernel P: fp32 x -> channel-paired f16x2 temp images ----------------
__global__ __launch_bounds__(256) void cvt_kernel(const float* __restrict__ x,
                                                  unsigned int* __restrict__ outU) {
  const int img = blockIdx.y;
  const int b = img / 28, cp = img % 28;
  const int p4 = (blockIdx.x * 256 + threadIdx.x) * 4;
  const float* x0 = x + ((size_t)b * 55 + 2*cp) * NPIX + p4;
  float4 a = *(const float4*)x0;
  float4 c = make_float4(0.f, 0.f, 0.f, 0.f);
  if (2*cp + 1 < 55) c = *(const float4*)(x0 + NPIX);
  uint4 w;
  w.x = __builtin_bit_cast(unsigned int, __builtin_amdgcn_cvt_pkrtz(a.x, c.x));
  w.y = __builtin_bit_cast(unsigned int, __builtin_amdgcn_cvt_pkrtz(a.y, c.y));
  w.z = __builtin_bit_cast(unsigned int, __builtin_amdgcn_cvt_pkrtz(a.z, c.z));
  w.w = __builtin_bit_cast(unsigned int, __builtin_amdgcn_cvt_pkrtz(a.w, c.w));
  *(uint4*)(outU + img_off(img) + p4) = w;
}

// ---------------- Kernel A: merged 3-dilation 5x5 conv via v_dot2_f32_f16 ----------------
// 512 threads, oc-SPLIT: waves 0-3 (half=0) do oc{0,1,2}, waves 4-7 do oc{3,4,5}
// of each dilation -> acc[9][4]=36 regs/thread: everything stays in VGPRs (no
// accvgpr round-trips, which cost ~220us in r10 at VGPR_Count=56).
// Tile 16x64; both halves consume the same staged LDS tile (stage once).
// Row stride 84 u32 (336B): bank offsets cycle 0,20,8,28,... -> kills the
// row-pair bank aliasing (3.1e7 conflict cycles at stride 80).
// LDS 2 x 588 chunks x 16B = 18.8 KB.
__global__ __attribute__((amdgpu_flat_work_group_size(512, 512)))
           __attribute__((amdgpu_waves_per_eu(2, 4)))
void conv_kernel(
    const unsigned int* __restrict__ xu, const unsigned int* __restrict__ wpku,
    const unsigned int* __restrict__ zp,
    const float* __restrict__ b1, const float* __restrict__ b2, const float* __restrict__ b3,
    float* __restrict__ out) {
  __shared__ __align__(16) unsigned int tile[2][2352];   // 28 rows x 84 u32 per buffer
  const int tid = threadIdx.x;
  const int half = tid >> 8;       // wave-uniform (waves 0-3 vs 4-7)
  const int t    = tid & 255;
  const int b  = blockIdx.z;
  const int h0 = blockIdx.y * 16;
  const int w0 = blockIdx.x * 64;

  auto STAGE = [&](int bufi, int cp) {
    const unsigned int* xc = xu + img_off(b*28 + cp);
    #pragma unroll
    for (int k = 0; k < 2; ++k) {
      int idx = k*512 + tid;                 // chunk 0..587 (28 rows x 21 chunks)
      if (idx < 588) {
        int row = idx / 21, cc = (idx % 21) * 4;
        int gh = h0 - 6 + row, gw = w0 - 8 + cc;
        bool ok = (gh >= 0) & (gh < 768) & (gw >= 0) & (gw + 3 < 768);
        const unsigned int* src = ok ? (xc + gh*768 + gw) : (zp + (tid & 63)*4);
        unsigned int* dst = &tile[bufi][(idx & ~63)*4];  // wave-uniform base
        __builtin_amdgcn_global_load_lds(
            (const __attribute__((address_space(1))) void*)src,
            (__attribute__((address_space(3))) void*)dst, 16, 0, 0);
      }
    }
  };

  float acc[9][4];
  #pragma unroll
  for (int i = 0; i < 9; ++i)
    #pragma unroll
    for (int p = 0; p < 4; ++p) acc[i][p] = 0.f;

  const int r6 = (t >> 4) + 6;     // tap-row base
  const int c  = t & 15;           // 4-px strip (quarter-wave = one LDS row)

#define TAPS(D, KY, BASE) \
  { const unsigned int* wr = wchp + ((D-1)*5 + (KY))*32 + 3*half; \
    _Pragma("unroll") for (int kx = 0; kx < 5; ++kx) { \
      _Pragma("unroll") for (int j = 0; j < 3; ++j) { \
        const half2v wv = h2(wr[kx*6+j]); \
        _Pragma("unroll") for (int p = 0; p < 4; ++p) \
          acc[(D-1)*3+j][p] = __builtin_amdgcn_fdot2( \
              h2(sp2[(BASE) + p + (kx-2)*(D)]), wv, acc[(D-1)*3+j][p], false); } } }

  // wide: 5 chunks from chunk (c+0) -> u32 [4c, 4c+20)   : tap base 8
  // med : 3 chunks from chunk (c+1) -> u32 [4c+4, 4c+16) : tap base 4
#define LOADW(O) { const uint4* rp = (const uint4*)&tb[(r6 + (O))*84] + c; \
    *(uint4*)&sp2[0]  = rp[0]; *(uint4*)&sp2[4]  = rp[1]; *(uint4*)&sp2[8] = rp[2]; \
    *(uint4*)&sp2[12] = rp[3]; *(uint4*)&sp2[16] = rp[4]; }
#define LOADM(O) { const uint4* rp = (const uint4*)&tb[(r6 + (O))*84] + c + 1; \
    *(uint4*)&sp2[0] = rp[0]; *(uint4*)&sp2[4] = rp[1]; *(uint4*)&sp2[8] = rp[2]; }

  STAGE(0, 0);
  __syncthreads();
  int cur = 0;
  for (int cp = 0; cp < 28; ++cp) {
    if (cp < 27) STAGE(cur ^ 1, cp + 1);    // loads in flight across the consume
    const unsigned int* tb = &tile[cur][0];
    const unsigned int* wchp = wpku + cp * 480;
    unsigned int sp2[20];
    LOADW(-6); TAPS(3,0,8)
    LOADM(-4); TAPS(2,0,4)
    LOADW(-3); TAPS(3,1,8)
    LOADM(-2); TAPS(1,0,4) TAPS(2,1,4)
    LOADM(-1); TAPS(1,1,4)
    LOADW( 0); TAPS(1,2,8) TAPS(2,2,8) TAPS(3,2,8)
    LOADM( 1); TAPS(1,3,4)
    LOADM( 2); TAPS(1,4,4) TAPS(2,3,4)
    LOADW( 3); TAPS(3,3,8)
    LOADM( 4); TAPS(2,4,4)
    LOADW( 6); TAPS(3,4,8)
    __syncthreads();
    cur ^= 1;
  }
#undef TAPS
#undef LOADW
#undef LOADM

  const int gr = h0 + (r6 - 6), gcol = w0 + c*4;
  #pragma unroll
  for (int d = 0; d < 3; ++d) {
    const float* bp = (d == 0) ? b1 : ((d == 1) ? b2 : b3);
    #pragma unroll
    for (int j = 0; j < 3; ++j) {
      const int ocg = 3*half + j;
      const float bias = bp[ocg];
      float4 v;
      v.x = fmaxf(acc[d*3+j][0] + bias, 0.f);
      v.y = fmaxf(acc[d*3+j][1] + bias, 0.f);
      v.z = fmaxf(acc[d*3+j][2] + bias, 0.f);
      v.w = fmaxf(acc[d*3+j][3] + bias, 0.f);
      *(float4*)(out + ((size_t)(b*55 + 36 + d*6 + ocg))*NPIX + gr*768 + gcol) = v;
    }
  }
}

// ---------------- Kernel B: per-cell sums of features + sigmoid(bot) ----------------
__global__ __launch_bounds__(256) void cellsum_kernel(const float* __restrict__ dout,
    const int* __restrict__ bounds,
    const float* __restrict__ w_bot, const float* __restrict__ b_bot,
    float* __restrict__ feat_sums, float* __restrict__ bot_partial) {
  int blk = blockIdx.x;                       // b*576 + r*24 + c
  int b = blk / NCELL; int rc = blk % NCELL; int r = rc / NCC, c = rc % NCC;
  int rs = bounds[r], re = bounds[24 + r], cs = bounds[48 + c], ce = bounds[72 + c];
  int cw = ce - cs;
  int npix = (re - rs) * cw;
  float facc[18];
  #pragma unroll
  for (int k = 0; k < 18; ++k) facc[k] = 0.f;
  float sacc = 0.f;
  float wb[18];
  #pragma unroll
  for (int k = 0; k < 18; ++k) wb[k] = w_bot[k];
  float bb = b_bot[0];
  const float* fb = dout + ((size_t)b * 55 + 36) * NPIX;
  for (int i = threadIdx.x; i < npix; i += 256) {
    int hh = rs + i / cw, ww = cs + i % cw;
    int pix = hh * WW + ww;
    float dot = bb;
    #pragma unroll
    for (int k = 0; k < 18; ++k) {
      float v = fb[(size_t)k * NPIX + pix];
      facc[k] += v;
      dot += wb[k] * v;
    }
    sacc += 1.f / (1.f + expf(-dot));
  }
  #pragma unroll
  for (int k = 0; k < 18; ++k) {
    #pragma unroll
    for (int off = 32; off; off >>= 1) facc[k] += __shfl_xor(facc[k], off);
  }
  #pragma unroll
  for (int off = 32; off; off >>= 1) sacc += __shfl_xor(sacc, off);
  __shared__ float red[4][19];
  int wv = threadIdx.x >> 6, ln = threadIdx.x & 63;
  if (ln == 0) {
    #pragma unroll
    for (int k = 0; k < 18; ++k) red[wv][k] = facc[k];
    red[wv][18] = sacc;
  }
  __syncthreads();
  if (threadIdx.x < 19) {
    float s = red[0][threadIdx.x] + red[1][threadIdx.x] + red[2][threadIdx.x] + red[3][threadIdx.x];
    if (threadIdx.x < 18) feat_sums[(size_t)blk * 18 + threadIdx.x] = s;
    else bot_partial[blk] = s;
  }
}

// ---------------- Kernel C: cell means (top) + pools ----------------
__global__ void cellmean_kernel(const float* __restrict__ feat_sums,
    const float* __restrict__ bot_partial, const int* __restrict__ bounds,
    const float* __restrict__ w_top, const float* __restrict__ b_top,
    float* __restrict__ top_means, float* __restrict__ pools_val, float* __restrict__ dout) {
  int t = blockIdx.x * 256 + threadIdx.x;
  if (t < NB * CTOPC * NCELL) {
    int c = t % NCC, r = (t / NCC) % NRR, k = (t / NCELL) % CTOPC, b = t / (NCELL * CTOPC);
    int cnt = (bounds[24 + r] - bounds[r]) * (bounds[72 + c] - bounds[48 + c]);
    float v = 0.f;
    if (cnt > 0) {
      const float* fs = feat_sums + ((size_t)(b * NCELL + r * NCC + c)) * 18;
      float dot = 0.f;
      #pragma unroll
      for (int i = 0; i < 18; ++i) dot += w_top[k * 18 + i] * fs[i];
      v = dot / (float)cnt + b_top[k];
    }
    top_means[t] = v;   // [b][k][r][c]
  }
  int t2 = t - NB * CTOPC * NCELL;
  if (t2 >= 0 && t2 < NCELL) {
    int r = t2 / NCC, c = t2 % NCC;
    int cnt = (bounds[24 + r] - bounds[r]) * (bounds[72 + c] - bounds[48 + c]);
    if (cnt < 1) cnt = 1;
    float v = (bot_partial[t2] + bot_partial[NCELL + t2]) / (2.f * (float)cnt);
    pools_val[t2] = v;
    dout[(size_t)NB * 55 * NPIX + t2] = v;           // pools b=0
    dout[(size_t)NB * 55 * NPIX + NCELL + t2] = v;   // pools b=1
  }
}

// ---------------- Kernel D: broadcast top means + bottom value ----------------
__global__ __launch_bounds__(256) void bcast_kernel(const float* __restrict__ top_means,
    const float* __restrict__ pools_val, const int* __restrict__ row_ids,
    const int* __restrict__ col_ids, float* __restrict__ out) {
  int w = blockIdx.x * 256 + threadIdx.x;
  int h = blockIdx.y;
  int b = blockIdx.z;
  int r = row_ids[h], c = col_ids[w];
  int pix = h * 768 + w;
  float* ob = out + (size_t)b * 55 * NPIX + pix;
  const float* tm = top_means + (size_t)b * CTOPC * NCELL + r * NCC + c;
  #pragma unroll
  for (int k = 0; k < 36; ++k) ob[(size_t)k * NPIX] = tm[(size_t)k * NCELL];
  ob[(size_t)54 * NPIX] = pools_val[r * NCC + c];
}

extern "C" void kernel_launch(void* const* d_in, const int* in_sizes, int n_in,
                              void* d_out, int out_size, void* d_ws, size_t ws_size,
                              hipStream_t stream) {
  const float* x      = (const float*)d_in[0];
  const int* row_ids  = (const int*)d_in[1];
  const int* col_ids  = (const int*)d_in[2];
  const float* w1     = (const float*)d_in[5];
  const float* b1     = (const float*)d_in[6];
  const float* w2     = (const float*)d_in[7];
  const float* b2     = (const float*)d_in[8];
  const float* w3     = (const float*)d_in[9];
  const float* b3     = (const float*)d_in[10];
  const float* w_top  = (const float*)d_in[11];
  const float* b_top  = (const float*)d_in[12];
  const float* w_bot  = (const float*)d_in[13];
  const float* b_bot  = (const float*)d_in[14];
  float* out = (float*)d_out;
  float* ws  = (float*)d_ws;

  unsigned int* wpku = (unsigned int*)(ws + OFF_WPKP);
  unsigned int* zp   = (unsigned int*)(ws + OFF_ZP);
  float* feat_sums   = ws + OFF_FSUM;
  float* bot_partial = ws + OFF_BOTP;
  float* top_means   = ws + OFF_TMEAN;
  float* pools_val   = ws + OFF_PVAL;
  int*   bounds      = (int*)(ws + OFF_BOUNDS);
  unsigned int* outU = (unsigned int*)d_out;

  hipLaunchKernelGGL(prep_kernel, dim3(53), dim3(256), 0, stream,
                     w1, w2, w3, row_ids, col_ids, wpku, zp, bounds);
  hipLaunchKernelGGL(cvt_kernel, dim3(576, 56), dim3(256), 0, stream,
                     x, outU);
  hipLaunchKernelGGL(conv_kernel, dim3(12, 48, 2), dim3(512), 0, stream,
                     outU, wpku, zp, b1, b2, b3, out);
  hipLaunchKernelGGL(cellsum_kernel, dim3(NB * NCELL), dim3(256), 0, stream,
                     out, bounds, w_bot, b_bot, feat_sums, bot_partial);
  hipLaunchKernelGGL(cellmean_kernel, dim3(165), dim3(256), 0, stream,
                     feat_sums, bot_partial, bounds, w_top, b_top, top_means, pools_val, out);
  hipLaunchKernelGGL(bcast_kernel, dim3(3, 768, 2), dim3(256), 0, stream,
                     top_means, pools_val, row_ids, col_ids, out);
}

// Round 12
// 640.881 us; speedup vs baseline: 1.7571x; 1.2038x over previous
//
#include <hip/hip_runtime.h>
#include <math.h>

#define HH 768
#define WW 768
#define NPIX (HH*WW)            // 589824
#define NRR 24
#define NCC 24
#define NCELL (NRR*NCC)         // 576
#define CTOPC 36
#define NB 2

typedef _Float16 half2v __attribute__((ext_vector_type(2)));
__device__ __forceinline__ half2v h2(unsigned int u) { return __builtin_bit_cast(half2v, u); }

// f16x2 temp images live in spare d_out regions: img i (=b*28+cp, NPIX u32 each):
// i<36 -> out image i (b0 ch0-35); i>=36 -> out image i+19 (b1 ch0-19).
// Disjoint from conv outputs (imgs 36-53, 91-108); fully overwritten by bcast later.
__device__ __host__ __forceinline__ size_t img_off(int i) {
  return (size_t)(i < 36 ? i : i + 19) * NPIX;
}

// ws layout (float offsets)
#define OFF_WPKP   0            // 28*480 = 13440 u32: [chpair][d][ky][kx*6+oc] packed f16x2
#define OFF_ZP     13440        // 256 u32 zeros (OOB staging target)
#define OFF_FSUM   13696        // 2*576*18 = 20736
#define OFF_BOTP   34432        // 1152
#define OFF_TMEAN  35584        // 2*36*576 = 41472
#define OFF_PVAL   77056        // 576
#define OFF_BOUNDS 77632        // 96 ints

// ---------------- Kernel 0: weight pack (f16x2 channel pairs) + bounds + zp ----------------
__global__ void prep_kernel(const float* __restrict__ w1, const float* __restrict__ w2,
                            const float* __restrict__ w3,
                            const int* __restrict__ row_ids, const int* __restrict__ col_ids,
                            unsigned int* __restrict__ wpku, unsigned int* __restrict__ zp,
                            int* __restrict__ bounds) {
  int t = blockIdx.x * 256 + threadIdx.x;
  if (t < 28*480) {
    int cp = t / 480; int r = t % 480;
    int d = r / 160; int r2 = r % 160;
    int ky = r2 / 32; int slot = r2 % 32;
    unsigned int v = 0;
    if (slot < 30) {
      int kx = slot / 6, oc = slot % 6;
      int ch0 = 2*cp, ch1 = ch0 + 1;
      const float* wsrc = (d == 0) ? w1 : ((d == 1) ? w2 : w3);
      float f0 = wsrc[((oc * 55 + ch0) * 5 + ky) * 5 + kx];
      float f1 = (ch1 < 55) ? wsrc[((oc * 55 + ch1) * 5 + ky) * 5 + kx] : 0.f;
      _Float16 g0 = (_Float16)f0, g1 = (_Float16)f1;   // RTNE
      unsigned short s0 = __builtin_bit_cast(unsigned short, g0);
      unsigned short s1 = __builtin_bit_cast(unsigned short, g1);
      v = (unsigned int)s0 | ((unsigned int)s1 << 16);
    }
    wpku[t] = v;
  }
  if (blockIdx.x == 1 && threadIdx.x < 256) zp[threadIdx.x] = 0u;
  if (blockIdx.x == 0 && threadIdx.x < 48) {
    int tt = threadIdx.x;
    const int* ids = (tt < 24) ? row_ids : col_ids;
    int r = tt % 24;
    int s = HH, e = HH;
    for (int h = 0; h < HH; ++h) {
      int v = ids[h];
      if (v >= r && h < s) s = h;
      if (v >= r + 1 && h < e) e = h;
    }
    int base = (tt < 24) ? 0 : 48;
    bounds[base + r] = s;
    bounds[base + 24 + r] = e;
  }
}

// ---------------- Kernel P: fp32 x -> channel-paired f16x2 temp images ----------------
__global__ __launch_bounds__(256) void cvt_kernel(const float* __restrict__ x,
                                                  unsigned int* __restrict__ outU) {
  const int img = blockIdx.y;
  const int b = img / 28, cp = img % 28;
  const int p4 = (blockIdx.x * 256 + threadIdx.x) * 4;
  const float* x0 = x + ((size_t)b * 55 + 2*cp) * NPIX + p4;
  float4 a = *(const float4*)x0;
  float4 c = make_float4(0.f, 0.f, 0.f, 0.f);
  if (2*cp + 1 < 55) c = *(const float4*)(x0 + NPIX);
  uint4 w;
  w.x = __builtin_bit_cast(unsigned int, __builtin_amdgcn_cvt_pkrtz(a.x, c.x));
  w.y = __builtin_bit_cast(unsigned int, __builtin_amdgcn_cvt_pkrtz(a.y, c.y));
  w.z = __builtin_bit_cast(unsigned int, __builtin_amdgcn_cvt_pkrtz(a.z, c.z));
  w.w = __builtin_bit_cast(unsigned int, __builtin_amdgcn_cvt_pkrtz(a.w, c.w));
  *(uint4*)(outU + img_off(img) + p4) = w;
}

// ---------------- Kernel A: merged conv, DILATION-SPLIT via v_dot2_f32_f16 ----------------
// 768 threads = 3 groups x 256; group g computes ONLY dilation g+1 (6 oc):
// acc[6][4] = 24 regs/thread -> no AGPR parking (r10/r11's hidden cost).
// Read duplication only 1.28x (dil1/2: 15 b128/phase, dil3: 25) vs oc-split's 2x.
// Same r10 schedule: global_load_lds double-buffered staging, 28 chpair phases.
// LDS 2 x 28 rows x 84 u32 = 18.4 KB. waves_per_eu(2,6): VGPR budget 85.
__global__ __attribute__((amdgpu_flat_work_group_size(768, 768)))
           __attribute__((amdgpu_waves_per_eu(2, 6)))
void conv_kernel(
    const unsigned int* __restrict__ xu, const unsigned int* __restrict__ wpku,
    const unsigned int* __restrict__ zp,
    const float* __restrict__ b1, const float* __restrict__ b2, const float* __restrict__ b3,
    float* __restrict__ out) {
  __shared__ __align__(16) unsigned int tile[2][2352];   // 28 rows x 84 u32 per buffer
  const int tid = threadIdx.x;
  const int g  = tid >> 8;         // dilation group 0..2 (wave-uniform)
  const int t  = tid & 255;
  const int b  = blockIdx.z;
  const int h0 = blockIdx.y * 16;
  const int w0 = blockIdx.x * 64;

  auto STAGE = [&](int bufi, int cp) {
    const unsigned int* xc = xu + img_off(b*28 + cp);
    if (tid < 588) {                       // 28 rows x 21 chunks
      int row = tid / 21, cc = (tid % 21) * 4;
      int gh = h0 - 6 + row, gw = w0 - 8 + cc;
      bool ok = (gh >= 0) & (gh < 768) & (gw >= 0) & (gw + 3 < 768);
      const unsigned int* src = ok ? (xc + gh*768 + gw) : (zp + (tid & 63)*4);
      unsigned int* dst = &tile[bufi][(tid & ~63)*4];  // wave-uniform base
      __builtin_amdgcn_global_load_lds(
          (const __attribute__((address_space(1))) void*)src,
          (__attribute__((address_space(3))) void*)dst, 16, 0, 0);
    }
  };

  float acc[6][4];
  #pragma unroll
  for (int i = 0; i < 6; ++i)
    #pragma unroll
    for (int p = 0; p < 4; ++p) acc[i][p] = 0.f;

  const int r6 = (t >> 4) + 6;     // tap-row base
  const int c  = t & 15;           // 4-px strip (quarter-wave = one LDS row)

  // TAPS for this group's dilation D, weights row ky; acc[oc] directly.
#define TAPSG(D, KY, BASE) \
  { const unsigned int* wr = wchp + ((D-1)*5 + (KY))*32; \
    _Pragma("unroll") for (int kx = 0; kx < 5; ++kx) { \
      _Pragma("unroll") for (int oc = 0; oc < 6; ++oc) { \
        const half2v wv = h2(wr[kx*6+oc]); \
        _Pragma("unroll") for (int p = 0; p < 4; ++p) \
          acc[oc][p] = __builtin_amdgcn_fdot2( \
              h2(sp2[(BASE) + p + (kx-2)*(D)]), wv, acc[oc][p], false); } } }

  // wide: 5 chunks from chunk (c+0) -> u32 [4c, 4c+20)   : tap base 8 (dil3)
  // med : 3 chunks from chunk (c+1) -> u32 [4c+4, 4c+16) : tap base 4 (dil1/2)
#define LOADW(O) { const uint4* rp = (const uint4*)&tb[(r6 + (O))*84] + c; \
    *(uint4*)&sp2[0]  = rp[0]; *(uint4*)&sp2[4]  = rp[1]; *(uint4*)&sp2[8] = rp[2]; \
    *(uint4*)&sp2[12] = rp[3]; *(uint4*)&sp2[16] = rp[4]; }
#define LOADM(O) { const uint4* rp = (const uint4*)&tb[(r6 + (O))*84] + c + 1; \
    *(uint4*)&sp2[0] = rp[0]; *(uint4*)&sp2[4] = rp[1]; *(uint4*)&sp2[8] = rp[2]; }

  STAGE(0, 0);
  __syncthreads();
  int cur = 0;
  for (int cp = 0; cp < 28; ++cp) {
    if (cp < 27) STAGE(cur ^ 1, cp + 1);    // loads in flight across the consume
    const unsigned int* tb = &tile[cur][0];
    const unsigned int* wchp = wpku + cp * 480;
    unsigned int sp2[20];
    if (g == 0) {            // dilation 1: rows -2..2, med spans
      LOADM(-2); TAPSG(1,0,4)
      LOADM(-1); TAPSG(1,1,4)
      LOADM( 0); TAPSG(1,2,4)
      LOADM( 1); TAPSG(1,3,4)
      LOADM( 2); TAPSG(1,4,4)
    } else if (g == 1) {     // dilation 2: rows -4,-2,0,2,4, med spans
      LOADM(-4); TAPSG(2,0,4)
      LOADM(-2); TAPSG(2,1,4)
      LOADM( 0); TAPSG(2,2,4)
      LOADM( 2); TAPSG(2,3,4)
      LOADM( 4); TAPSG(2,4,4)
    } else {                 // dilation 3: rows -6,-3,0,3,6, wide spans
      LOADW(-6); TAPSG(3,0,8)
      LOADW(-3); TAPSG(3,1,8)
      LOADW( 0); TAPSG(3,2,8)
      LOADW( 3); TAPSG(3,3,8)
      LOADW( 6); TAPSG(3,4,8)
    }
    __syncthreads();
    cur ^= 1;
  }
#undef TAPSG
#undef LOADW
#undef LOADM

  const int gr = h0 + (r6 - 6), gcol = w0 + c*4;
  const float* bp = (g == 0) ? b1 : ((g == 1) ? b2 : b3);
  #pragma unroll
  for (int oc = 0; oc < 6; ++oc) {
    const float bias = bp[oc];
    float4 v;
    v.x = fmaxf(acc[oc][0] + bias, 0.f);
    v.y = fmaxf(acc[oc][1] + bias, 0.f);
    v.z = fmaxf(acc[oc][2] + bias, 0.f);
    v.w = fmaxf(acc[oc][3] + bias, 0.f);
    *(float4*)(out + ((size_t)(b*55 + 36 + g*6 + oc))*NPIX + gr*768 + gcol) = v;
  }
}

// ---------------- Kernel B: per-cell sums of features + sigmoid(bot) ----------------
__global__ __launch_bounds__(256) void cellsum_kernel(const float* __restrict__ dout,
    const int* __restrict__ bounds,
    const float* __restrict__ w_bot, const float* __restrict__ b_bot,
    float* __restrict__ feat_sums, float* __restrict__ bot_partial) {
  int blk = blockIdx.x;                       // b*576 + r*24 + c
  int b = blk / NCELL; int rc = blk % NCELL; int r = rc / NCC, c = rc % NCC;
  int rs = bounds[r], re = bounds[24 + r], cs = bounds[48 + c], ce = bounds[72 + c];
  int cw = ce - cs;
  int npix = (re - rs) * cw;
  float facc[18];
  #pragma unroll
  for (int k = 0; k < 18; ++k) facc[k] = 0.f;
  float sacc = 0.f;
  float wb[18];
  #pragma unroll
  for (int k = 0; k < 18; ++k) wb[k] = w_bot[k];
  float bb = b_bot[0];
  const float* fb = dout + ((size_t)b * 55 + 36) * NPIX;
  for (int i = threadIdx.x; i < npix; i += 256) {
    int hh = rs + i / cw, ww = cs + i % cw;
    int pix = hh * WW + ww;
    float dot = bb;
    #pragma unroll
    for (int k = 0; k < 18; ++k) {
      float v = fb[(size_t)k * NPIX + pix];
      facc[k] += v;
      dot += wb[k] * v;
    }
    sacc += 1.f / (1.f + expf(-dot));
  }
  #pragma unroll
  for (int k = 0; k < 18; ++k) {
    #pragma unroll
    for (int off = 32; off; off >>= 1) facc[k] += __shfl_xor(facc[k], off);
  }
  #pragma unroll
  for (int off = 32; off; off >>= 1) sacc += __shfl_xor(sacc, off);
  __shared__ float red[4][19];
  int wv = threadIdx.x >> 6, ln = threadIdx.x & 63;
  if (ln == 0) {
    #pragma unroll
    for (int k = 0; k < 18; ++k) red[wv][k] = facc[k];
    red[wv][18] = sacc;
  }
  __syncthreads();
  if (threadIdx.x < 19) {
    float s = red[0][threadIdx.x] + red[1][threadIdx.x] + red[2][threadIdx.x] + red[3][threadIdx.x];
    if (threadIdx.x < 18) feat_sums[(size_t)blk * 18 + threadIdx.x] = s;
    else bot_partial[blk] = s;
  }
}

// ---------------- Kernel C: cell means (top) + pools ----------------
__global__ void cellmean_kernel(const float* __restrict__ feat_sums,
    const float* __restrict__ bot_partial, const int* __restrict__ bounds,
    const float* __restrict__ w_top, const float* __restrict__ b_top,
    float* __restrict__ top_means, float* __restrict__ pools_val, float* __restrict__ dout) {
  int t = blockIdx.x * 256 + threadIdx.x;
  if (t < NB * CTOPC * NCELL) {
    int c = t % NCC, r = (t / NCC) % NRR, k = (t / NCELL) % CTOPC, b = t / (NCELL * CTOPC);
    int cnt = (bounds[24 + r] - bounds[r]) * (bounds[72 + c] - bounds[48 + c]);
    float v = 0.f;
    if (cnt > 0) {
      const float* fs = feat_sums + ((size_t)(b * NCELL + r * NCC + c)) * 18;
      float dot = 0.f;
      #pragma unroll
      for (int i = 0; i < 18; ++i) dot += w_top[k * 18 + i] * fs[i];
      v = dot / (float)cnt + b_top[k];
    }
    top_means[t] = v;   // [b][k][r][c]
  }
  int t2 = t - NB * CTOPC * NCELL;
  if (t2 >= 0 && t2 < NCELL) {
    int r = t2 / NCC, c = t2 % NCC;
    int cnt = (bounds[24 + r] - bounds[r]) * (bounds[72 + c] - bounds[48 + c]);
    if (cnt < 1) cnt = 1;
    float v = (bot_partial[t2] + bot_partial[NCELL + t2]) / (2.f * (float)cnt);
    pools_val[t2] = v;
    dout[(size_t)NB * 55 * NPIX + t2] = v;           // pools b=0
    dout[(size_t)NB * 55 * NPIX + NCELL + t2] = v;   // pools b=1
  }
}

// ---------------- Kernel D: broadcast top means + bottom value ----------------
__global__ __launch_bounds__(256) void bcast_kernel(const float* __restrict__ top_means,
    const float* __restrict__ pools_val, const int* __restrict__ row_ids,
    const int* __restrict__ col_ids, float* __restrict__ out) {
  int w = blockIdx.x * 256 + threadIdx.x;
  int h = blockIdx.y;
  int b = blockIdx.z;
  int r = row_ids[h], c = col_ids[w];
  int pix = h * 768 + w;
  float* ob = out + (size_t)b * 55 * NPIX + pix;
  const float* tm = top_means + (size_t)b * CTOPC * NCELL + r * NCC + c;
  #pragma unroll
  for (int k = 0; k < 36; ++k) ob[(size_t)k * NPIX] = tm[(size_t)k * NCELL];
  ob[(size_t)54 * NPIX] = pools_val[r * NCC + c];
}

extern "C" void kernel_launch(void* const* d_in, const int* in_sizes, int n_in,
                              void* d_out, int out_size, void* d_ws, size_t ws_size,
                              hipStream_t stream) {
  const float* x      = (const float*)d_in[0];
  const int* row_ids  = (const int*)d_in[1];
  const int* col_ids  = (const int*)d_in[2];
  const float* w1     = (const float*)d_in[5];
  const float* b1     = (const float*)d_in[6];
  const float* w2     = (const float*)d_in[7];
  const float* b2     = (const float*)d_in[8];
  const float* w3     = (const float*)d_in[9];
  const float* b3     = (const float*)d_in[10];
  const float* w_top  = (const float*)d_in[11];
  const float* b_top  = (const float*)d_in[12];
  const float* w_bot  = (const float*)d_in[13];
  const float* b_bot  = (const float*)d_in[14];
  float* out = (float*)d_out;
  float* ws  = (float*)d_ws;

  unsigned int* wpku = (unsigned int*)(ws + OFF_WPKP);
  unsigned int* zp   = (unsigned int*)(ws + OFF_ZP);
  float* feat_sums   = ws + OFF_FSUM;
  float* bot_partial = ws + OFF_BOTP;
  float* top_means   = ws + OFF_TMEAN;
  float* pools_val   = ws + OFF_PVAL;
  int*   bounds      = (int*)(ws + OFF_BOUNDS);
  unsigned int* outU = (unsigned int*)d_out;

  hipLaunchKernelGGL(prep_kernel, dim3(53), dim3(256), 0, stream,
                     w1, w2, w3, row_ids, col_ids, wpku, zp, bounds);
  hipLaunchKernelGGL(cvt_kernel, dim3(576, 56), dim3(256), 0, stream,
                     x, outU);
  hipLaunchKernelGGL(conv_kernel, dim3(12, 48, 2), dim3(768), 0, stream,
                     outU, wpku, zp, b1, b2, b3, out);
  hipLaunchKernelGGL(cellsum_kernel, dim3(NB * NCELL), dim3(256), 0, stream,
                     out, bounds, w_bot, b_bot, feat_sums, bot_partial);
  hipLaunchKernelGGL(cellmean_kernel, dim3(165), dim3(256), 0, stream,
                     feat_sums, bot_partial, bounds, w_top, b_top, top_means, pools_val, out);
  hipLaunchKernelGGL(bcast_kernel, dim3(3, 768, 2), dim3(256), 0, stream,
                     top_means, pools_val, row_ids, col_ids, out);
}